// Round 2
// 105.952 us; speedup vs baseline: 1.0742x; 1.0742x over previous
//
#include <hip/hip_runtime.h>
#include <hip/hip_fp16.h>
#include <stdint.h>

// Problem constants: B=32, N=2048, L=32768, D_IN=4, D=64
#define B_ 32
#define N_ 2048
#define L_ 32768

// Workspace: splatted half2 weight table, 64 features x 12 half2 (48 B each):
//   [f*12 + 0..3] : {wc1[i][f], wc1[i][f]} for input dim i of src node
//   [f*12 + 4..7] : same for dst node (wc2)
//   [f*12 + 8]    : {bias[f], bias[f]}   (b_embed@(W1_top+W1_bot)+b1)
//   [f*12 + 9]    : {W2[f][2], W2[f][2]}
//   [f*12 + 10]   : {W2[f][3], W2[f][3]}
//   [f*12 + 11]   : pad
// wc1 = W_embed@W1_top, wc2 = W_embed@W1_bot.

static __device__ __forceinline__ __half2 pkrtz(float a, float b) {
    return __float22half2_rn(make_float2(a, b));
}

static __device__ __forceinline__ __half2 pkmax(__half2 a, __half2 b) {
    __half2 r;
    asm("v_pk_max_f16 %0, %1, %2" : "=v"(r) : "v"(a), "v"(b));
    return r;
}

// ---------------- Kernel A: fold linears, emit splatted half2 table ---------
__global__ __launch_bounds__(512) void prep_kernel(
    const float* __restrict__ W_embed, const float* __restrict__ b_embed,
    const float* __restrict__ W1, const float* __restrict__ b1,
    const float* __restrict__ W2, __half2* __restrict__ wh) {
    __shared__ float sacc[64][8];
    __shared__ float sbias[64];
    int tid = threadIdx.x;
    int d = tid & 63;          // feature column (lane)
    int i = (tid >> 6) & 3;    // input dim (wave-uniform)
    int half_ = tid >> 8;      // 0 = top (src), 1 = bot (dst)

    const float* w1base = W1 + (half_ ? 64 * 64 : 0);
    float acc = 0.f;
#pragma unroll
    for (int k = 0; k < 64; ++k) {
        acc = fmaf(W_embed[i * 64 + k], w1base[k * 64 + d], acc);
    }
    sacc[d][half_ * 4 + i] = acc;

    if (tid < 64) {  // merged bias
        float bb = 0.f;
#pragma unroll
        for (int k = 0; k < 64; ++k) {
            bb = fmaf(b_embed[k], W1[k * 64 + d] + W1[(64 + k) * 64 + d], bb);
        }
        sbias[d] = bb + b1[d];
    }
    __syncthreads();

    if (tid < 64) {  // pack feature f = tid, everything splatted {v,v}
#pragma unroll
        for (int k = 0; k < 8; ++k) {
            float v = sacc[tid][k];
            wh[tid * 12 + k] = pkrtz(v, v);
        }
        float bv = sbias[tid];
        wh[tid * 12 + 8] = pkrtz(bv, bv);
        float c2 = W2[tid * 4 + 2];
        float c3 = W2[tid * 4 + 3];
        wh[tid * 12 + 9] = pkrtz(c2, c2);
        wh[tid * 12 + 10] = pkrtz(c3, c3);
        wh[tid * 12 + 11] = pkrtz(0.f, 0.f);
    }
}

// ---------------- Kernel B: per-edge, edge-pair-packed fp16 compute ---------
// 4 edges/thread (2 half2 edge-pairs); 1024 blocks -> 4 blocks/CU, 4 waves/SIMD.
// Nodes staged in LDS (fp32 float4). Each half2 lane-slot carries TWO edges;
// weights are wave-uniform splats ({w,w}) fetched via s_load. Per feature:
// 8 pk_fma + 1 pk_max (relu) + 2 pk_fma (head) = 11 pk ops for 2 edges.
__global__ __launch_bounds__(256, 4) void edge_kernel(
    const float4* __restrict__ pred_node,  // (B*N) float4 rows
    const __half2* __restrict__ wh,
    const int* __restrict__ esrc, const int* __restrict__ edst,
    const float2* __restrict__ lp2,        // line_param as float2 pairs
    const float* __restrict__ b2,
    float4* __restrict__ out) {
    __shared__ float4 spn[N_];  // 32 KB: this batch's pred_node

    int tid = threadIdx.x;
    int bid = blockIdx.x;       // 0..1023
    int x = bid & 7;            // XCD (dispatch round-robin heuristic)
    int i = bid >> 3;           // 0..127
    int b = x + 8 * (i >> 5);   // batch: 4 batches per XCD
    int j = i & 31;             // block within batch (32 blocks x 1024 edges)

    // ---- stage pred_node[b] into LDS (coalesced float4) ----
    const float4* pnb = pred_node + b * N_;
#pragma unroll
    for (int q = 0; q < 8; ++q) {
        int idx = tid + q * 256;
        spn[idx] = pnb[idx];
    }

    int ebase = b * L_ + j * 1024 + tid;

    // ---- preload this thread's 4 edge index pairs ----
    int sa[4], ta[4];
#pragma unroll
    for (int p = 0; p < 4; ++p) {
        int e = ebase + p * 256;
        sa[p] = esrc[e];
        ta[p] = edst[e];
    }
    float bias2 = b2[2], bias3 = b2[3];  // uniform -> s_load

    __syncthreads();  // staging complete

    // ---- gather node pairs; pack TWO EDGES per half2 slot ----
    // pair pr covers edges p=2pr (low half) and p=2pr+1 (high half)
    __half2 px[2][8];
#pragma unroll
    for (int pr = 0; pr < 2; ++pr) {
        float4 s0 = spn[sa[2 * pr]];
        float4 s1 = spn[sa[2 * pr + 1]];
        float4 t0 = spn[ta[2 * pr]];
        float4 t1 = spn[ta[2 * pr + 1]];
        px[pr][0] = pkrtz(s0.x, s1.x);
        px[pr][1] = pkrtz(s0.y, s1.y);
        px[pr][2] = pkrtz(s0.z, s1.z);
        px[pr][3] = pkrtz(s0.w, s1.w);
        px[pr][4] = pkrtz(t0.x, t1.x);
        px[pr][5] = pkrtz(t0.y, t1.y);
        px[pr][6] = pkrtz(t0.z, t1.z);
        px[pr][7] = pkrtz(t0.w, t1.w);
    }

    const __half2 zero = pkrtz(0.f, 0.f);
    __half2 acc2[2] = {zero, zero};
    __half2 acc3[2] = {zero, zero};

#pragma unroll 4
    for (int f = 0; f < 64; ++f) {  // one feature at a time, weights uniform
        const __half2* wf = wh + f * 12;
        __half2 w0 = wf[0], w1 = wf[1], w2w = wf[2], w3w = wf[3];
        __half2 w4 = wf[4], w5 = wf[5], w6w = wf[6], w7w = wf[7];
        __half2 bs = wf[8];
        __half2 c2 = wf[9], c3 = wf[10];
#pragma unroll
        for (int pr = 0; pr < 2; ++pr) {
            __half2 h = bs;
            h = __hfma2(px[pr][0], w0, h);
            h = __hfma2(px[pr][1], w1, h);
            h = __hfma2(px[pr][2], w2w, h);
            h = __hfma2(px[pr][3], w3w, h);
            h = __hfma2(px[pr][4], w4, h);
            h = __hfma2(px[pr][5], w5, h);
            h = __hfma2(px[pr][6], w6w, h);
            h = __hfma2(px[pr][7], w7w, h);
            h = pkmax(h, zero);  // relu, single VOP3P
            acc2[pr] = __hfma2(h, c2, acc2[pr]);
            acc3[pr] = __hfma2(h, c3, acc3[pr]);
        }
    }

    // ---- epilogue: lp loads late (fewer live regs in main loop) ----
#pragma unroll
    for (int p = 0; p < 4; ++p) {
        int e = ebase + p * 256;
        float2 lp = lp2[(size_t)e * 2];  // line_param[e][0:2]
        int pr = p >> 1;
        float r2 = (p & 1) ? __high2float(acc2[pr]) : __low2float(acc2[pr]);
        float r3 = (p & 1) ? __high2float(acc3[pr]) : __low2float(acc3[pr]);
        out[e] = make_float4(lp.x, lp.y, bias2 + r2, bias3 + r3);
    }
}

extern "C" void kernel_launch(void* const* d_in, const int* in_sizes, int n_in,
                              void* d_out, int out_size, void* d_ws, size_t ws_size,
                              hipStream_t stream) {
    const float* pred_node = (const float*)d_in[0];   // (B,N,4)
    const float* line_param = (const float*)d_in[1];  // (B,L,4)
    const float* W_embed = (const float*)d_in[2];     // (4,64)
    const float* b_embed = (const float*)d_in[3];     // (64,)
    const float* W1 = (const float*)d_in[4];          // (128,64)
    const float* b1 = (const float*)d_in[5];          // (64,)
    const float* W2 = (const float*)d_in[6];          // (64,4)
    const float* b2 = (const float*)d_in[7];          // (4,)
    const int* esrc = (const int*)d_in[8];            // (B,L)
    const int* edst = (const int*)d_in[9];            // (B,L)
    float* out = (float*)d_out;                       // (B,L,4)

    __half2* wh = (__half2*)d_ws;

    prep_kernel<<<1, 512, 0, stream>>>(W_embed, b_embed, W1, b1, W2, wh);
    edge_kernel<<<1024, 256, 0, stream>>>((const float4*)pred_node, wh,
                                          esrc, edst,
                                          (const float2*)line_param, b2,
                                          (float4*)out);
}